// Round 2
// baseline (381.234 us; speedup 1.0000x reference)
//
#include <hip/hip_runtime.h>
#include <hip/hip_bf16.h>

// OneStep: out = W - c * K^T (K W - V),  c = 0.2/(CTX*D) = 9.5367431640625e-8
// W: (4096,4096) fp32, keys: (512,4096) fp32, vals: (512,4096) fp32, out fp32.
// R0 post-mortem: inputs ARE fp32 (NaN from u16 reinterpretation proved it).
// Strategy: convert fp32->bf16 on the fly, bf16 MFMA with fp32 accumulation;
// update-term error ~1e-8 absolute, threshold 1.69e-3.

typedef __bf16 bf16_t;
typedef __bf16 bf16x8 __attribute__((ext_vector_type(8)));
typedef float f32x4 __attribute__((ext_vector_type(4)));

#define D_DIM 4096
#define CTX_N 512
#define UPD_SCALE 9.5367431640625e-8f

// Verified gfx950 16x16x32 bf16 MFMA layouts (learn_hip m89/m91):
//   A-frag / B-frag: element (row = lane&15, k = (lane>>4)*8 + j), 8 bf16/lane
//   C/D:             element (col = lane&15, row = (lane>>4)*4 + reg)
//   D[m][n] = sum_k Afrag(m,k) * Bfrag(n,k)

// ---------------- Kernel 1: R = bf16(K @ W - V)  (CTX x D) ----------------
__global__ __launch_bounds__(256) void k1_residual(
    const float* __restrict__ K, const float* __restrict__ W,
    const float* __restrict__ V, bf16_t* __restrict__ R)
{
    __shared__ __align__(16) bf16_t As[64 * 32];  // As[m][k]  (keys rows)
    __shared__ __align__(16) bf16_t Bs[64 * 32];  // Bs[n][k] = W[k][n]

    const int tid  = threadIdx.x;
    const int n0   = blockIdx.x * 64;   // j over D
    const int m0   = blockIdx.y * 64;   // c over CTX
    const int wave = tid >> 6, lane = tid & 63;
    const int wm = (wave >> 1) * 32, wn = (wave & 1) * 32;
    const int l15 = lane & 15, quad = lane >> 4;

    f32x4 acc[2][2] = {};

    const int a_row = tid >> 2, a_seg = (tid & 3) * 8;  // 64 rows x 4 segs of 8
    const int b_k   = tid >> 3, b_seg = (tid & 7) * 8;  // 32 k    x 8 segs of 8

    for (int kk0 = 0; kk0 < D_DIM; kk0 += 32) {
        // keys tile: row-major fp32, convert 8 -> one 16B LDS store
        {
            const float4 f0 = *(const float4*)(K + (size_t)(m0 + a_row) * D_DIM + kk0 + a_seg);
            const float4 f1 = *(const float4*)(K + (size_t)(m0 + a_row) * D_DIM + kk0 + a_seg + 4);
            bf16x8 v;
            v[0] = (bf16_t)f0.x; v[1] = (bf16_t)f0.y; v[2] = (bf16_t)f0.z; v[3] = (bf16_t)f0.w;
            v[4] = (bf16_t)f1.x; v[5] = (bf16_t)f1.y; v[6] = (bf16_t)f1.z; v[7] = (bf16_t)f1.w;
            *(bf16x8*)(&As[a_row * 32 + a_seg]) = v;
        }
        // W tile: read W[k][n] coalesced fp32, convert, transpose into Bs[n][k]
        {
            const float4 f0 = *(const float4*)(W + (size_t)(kk0 + b_k) * D_DIM + n0 + b_seg);
            const float4 f1 = *(const float4*)(W + (size_t)(kk0 + b_k) * D_DIM + n0 + b_seg + 4);
            const float f[8] = {f0.x, f0.y, f0.z, f0.w, f1.x, f1.y, f1.z, f1.w};
#pragma unroll
            for (int u = 0; u < 8; ++u) Bs[(b_seg + u) * 32 + b_k] = (bf16_t)f[u];
        }
        __syncthreads();

        const bf16x8 a0 = *(const bf16x8*)(&As[(wm + 0  + l15) * 32 + quad * 8]);
        const bf16x8 a1 = *(const bf16x8*)(&As[(wm + 16 + l15) * 32 + quad * 8]);
        const bf16x8 b0 = *(const bf16x8*)(&Bs[(wn + 0  + l15) * 32 + quad * 8]);
        const bf16x8 b1 = *(const bf16x8*)(&Bs[(wn + 16 + l15) * 32 + quad * 8]);
        acc[0][0] = __builtin_amdgcn_mfma_f32_16x16x32_bf16(a0, b0, acc[0][0], 0, 0, 0);
        acc[0][1] = __builtin_amdgcn_mfma_f32_16x16x32_bf16(a0, b1, acc[0][1], 0, 0, 0);
        acc[1][0] = __builtin_amdgcn_mfma_f32_16x16x32_bf16(a1, b0, acc[1][0], 0, 0, 0);
        acc[1][1] = __builtin_amdgcn_mfma_f32_16x16x32_bf16(a1, b1, acc[1][1], 0, 0, 0);
        __syncthreads();
    }

#pragma unroll
    for (int im = 0; im < 2; ++im)
#pragma unroll
        for (int in = 0; in < 2; ++in)
#pragma unroll
            for (int r = 0; r < 4; ++r) {
                const int row = m0 + wm + im * 16 + quad * 4 + r;
                const int col = n0 + wn + in * 16 + l15;
                const size_t idx = (size_t)row * D_DIM + col;
                R[idx] = (bf16_t)(acc[im][in][r] - V[idx]);
            }
}

// ---------------- Kernel 2: out = W - c * K^T @ R  (D x D) ----------------
__global__ __launch_bounds__(256) void k2_update(
    const float* __restrict__ K, const bf16_t* __restrict__ R,
    const float* __restrict__ W, float* __restrict__ out)
{
    __shared__ __align__(16) bf16_t As[64 * 32];  // As[i][c] = K[c][i]
    __shared__ __align__(16) bf16_t Bs[64 * 32];  // Bs[j][c] = R[c][j]

    const int tid  = threadIdx.x;
    const int j0   = blockIdx.x * 64;
    const int i0   = blockIdx.y * 64;
    const int wave = tid >> 6, lane = tid & 63;
    const int wm = (wave >> 1) * 32, wn = (wave & 1) * 32;
    const int l15 = lane & 15, quad = lane >> 4;

    f32x4 acc[2][2] = {};

    const int s_c = tid >> 3, s_seg = (tid & 7) * 8;  // 32 c x 8 segs of 8

    for (int c0 = 0; c0 < CTX_N; c0 += 32) {
        // K tile: read K[c][i] coalesced fp32, convert, transpose into As[i][c]
        {
            const float4 f0 = *(const float4*)(K + (size_t)(c0 + s_c) * D_DIM + i0 + s_seg);
            const float4 f1 = *(const float4*)(K + (size_t)(c0 + s_c) * D_DIM + i0 + s_seg + 4);
            const float f[8] = {f0.x, f0.y, f0.z, f0.w, f1.x, f1.y, f1.z, f1.w};
#pragma unroll
            for (int u = 0; u < 8; ++u) As[(s_seg + u) * 32 + s_c] = (bf16_t)f[u];
        }
        // R tile: bf16 already, read 8 contiguous, transpose into Bs[j][c]
        {
            const bf16x8 v = *(const bf16x8*)(R + (size_t)(c0 + s_c) * D_DIM + j0 + s_seg);
#pragma unroll
            for (int u = 0; u < 8; ++u) Bs[(s_seg + u) * 32 + s_c] = v[u];
        }
        __syncthreads();

        const bf16x8 a0 = *(const bf16x8*)(&As[(wm + 0  + l15) * 32 + quad * 8]);
        const bf16x8 a1 = *(const bf16x8*)(&As[(wm + 16 + l15) * 32 + quad * 8]);
        const bf16x8 b0 = *(const bf16x8*)(&Bs[(wn + 0  + l15) * 32 + quad * 8]);
        const bf16x8 b1 = *(const bf16x8*)(&Bs[(wn + 16 + l15) * 32 + quad * 8]);
        acc[0][0] = __builtin_amdgcn_mfma_f32_16x16x32_bf16(a0, b0, acc[0][0], 0, 0, 0);
        acc[0][1] = __builtin_amdgcn_mfma_f32_16x16x32_bf16(a0, b1, acc[0][1], 0, 0, 0);
        acc[1][0] = __builtin_amdgcn_mfma_f32_16x16x32_bf16(a1, b0, acc[1][0], 0, 0, 0);
        acc[1][1] = __builtin_amdgcn_mfma_f32_16x16x32_bf16(a1, b1, acc[1][1], 0, 0, 0);
        __syncthreads();
    }

#pragma unroll
    for (int im = 0; im < 2; ++im)
#pragma unroll
        for (int in = 0; in < 2; ++in)
#pragma unroll
            for (int r = 0; r < 4; ++r) {
                const int row = i0 + wm + im * 16 + quad * 4 + r;
                const int col = j0 + wn + in * 16 + l15;
                const size_t idx = (size_t)row * D_DIM + col;
                out[idx] = W[idx] - UPD_SCALE * acc[im][in][r];
            }
}

extern "C" void kernel_launch(void* const* d_in, const int* in_sizes, int n_in,
                              void* d_out, int out_size, void* d_ws, size_t ws_size,
                              hipStream_t stream) {
    const float* W = (const float*)d_in[0];   // (4096, 4096)
    const float* K = (const float*)d_in[1];   // (512, 4096)
    const float* V = (const float*)d_in[2];   // (512, 4096)
    float* out = (float*)d_out;
    bf16_t* R  = (bf16_t*)d_ws;               // (512, 4096) bf16 residual, 4 MB

    k1_residual<<<dim3(D_DIM / 64, CTX_N / 64), 256, 0, stream>>>(K, W, V, R);
    k2_update  <<<dim3(D_DIM / 64, D_DIM / 64), 256, 0, stream>>>(K, R, W, out);
}

// Round 3
// 231.268 us; speedup vs baseline: 1.6485x; 1.6485x over previous
//
#include <hip/hip_runtime.h>
#include <hip/hip_bf16.h>

// OneStep: out = W - c * K^T (K W - V),  c = 0.2/(CTX*D) = 9.5367431640625e-8
// W:(4096,4096) K:(512,4096) V:(512,4096) fp32 -> out (4096,4096) fp32.
// Harness compares on the bf16 grid (threshold ~7 ulp); bf16 MFMA w/ fp32 acc
// keeps us at 1 ulp (R2 measured 2.441e-4 = 2^-12 exactly).
//
// R2 post-mortem: both GEMMs were latency-bound on 16-way-conflicted scalar
// u16 LDS transpose scatters (SQ_LDS_BANK_CONFLICT=3.4e7, VALUBusy 6%).
// R3: pre-transpose/convert once (LDS-tiled, conflict-free), then both GEMMs
// read k-contiguous rows only, staged via global_load_lds width=16 (m97).

typedef __bf16 bf16_t;
typedef __bf16 bf16x8 __attribute__((ext_vector_type(8)));
typedef float f32x4 __attribute__((ext_vector_type(4)));

#define D_DIM 4096
#define CTX_N 512
#define UPD_SCALE 9.5367431640625e-8f

__device__ __forceinline__ void gld16(const bf16_t* g, bf16_t* l) {
    __builtin_amdgcn_global_load_lds(
        (const __attribute__((address_space(1))) void*)g,
        (__attribute__((address_space(3))) void*)l, 16, 0, 0);
}

// ---- T: src (M x N) fp32 -> dstT (N x M) bf16 [+ dstN (M x N) bf16] ----
// 64x64 tiles; LDS pad 65 => column gather banks = (k + rr) mod 32, 2-way free.
__global__ __launch_bounds__(256) void t_conv(
    const float* __restrict__ src, bf16_t* __restrict__ dstT,
    bf16_t* __restrict__ dstN, int M, int N)
{
    __shared__ float tile[64 * 65];
    const int tid = threadIdx.x;
    const int C0 = blockIdx.x * 64;   // col base (N dim)
    const int R0 = blockIdx.y * 64;   // row base (M dim)
    const int r  = tid >> 2, cs = (tid & 3) * 16;

    const float* s = src + (size_t)(R0 + r) * N + C0 + cs;
    float f[16];
#pragma unroll
    for (int u = 0; u < 4; ++u) {
        const float4 v = ((const float4*)s)[u];
        f[4 * u + 0] = v.x; f[4 * u + 1] = v.y; f[4 * u + 2] = v.z; f[4 * u + 3] = v.w;
    }
#pragma unroll
    for (int u = 0; u < 16; ++u) tile[r * 65 + cs + u] = f[u];

    if (dstN) {
        bf16x8 v0, v1;
#pragma unroll
        for (int u = 0; u < 8; ++u) { v0[u] = (bf16_t)f[u]; v1[u] = (bf16_t)f[8 + u]; }
        bf16_t* d = dstN + (size_t)(R0 + r) * N + C0 + cs;
        *(bf16x8*)d = v0; *(bf16x8*)(d + 8) = v1;
    }
    __syncthreads();

    // output row (C0+rr) of dstT, cols R0+k0..k0+15
    const int rr = tid >> 2, k0 = (tid & 3) * 16;
    bf16x8 o0, o1;
#pragma unroll
    for (int u = 0; u < 8; ++u) {
        o0[u] = (bf16_t)tile[(k0 + u) * 65 + rr];
        o1[u] = (bf16_t)tile[(k0 + 8 + u) * 65 + rr];
    }
    bf16_t* d = dstT + (size_t)(C0 + rr) * M + R0 + k0;
    *(bf16x8*)d = o0; *(bf16x8*)(d + 8) = o1;
}

// ---- K1: Rt[j][c] = sum_k Wt[j][k]*Kb[c][k] - Vt[j][c]  (4096 x 512) ----
// MFMA 16x16x32 bf16 (m89/m91): Afrag(m,k)/Bfrag(n,k): row=lane&15,k=quad*8+j;
// C/D: col=lane&15, row=quad*4+reg.
__global__ __launch_bounds__(256) void k1_residual(
    const bf16_t* __restrict__ Wt, const bf16_t* __restrict__ Kb,
    const bf16_t* __restrict__ Vt, bf16_t* __restrict__ Rt)
{
    __shared__ __align__(16) bf16_t As[64 * 32];  // Wt rows (j, k)
    __shared__ __align__(16) bf16_t Bs[64 * 32];  // Kb rows (c, k)

    const int tid = threadIdx.x;
    const int j0 = blockIdx.x * 64;   // x = j so the 8 c-sharers co-locate per XCD
    const int c0 = blockIdx.y * 64;
    const int lane = tid & 63, wave = tid >> 6;
    const int wm = (wave >> 1) * 32, wn = (wave & 1) * 32;
    const int l15 = lane & 15, quad = lane >> 4;

    f32x4 acc[2][2] = {};

    const int srow = tid >> 2, sseg = (tid & 3) * 8;
    const bf16_t* ga = Wt + (size_t)(j0 + srow) * D_DIM + sseg;
    const bf16_t* gb = Kb + (size_t)(c0 + srow) * D_DIM + sseg;
    bf16_t* la = (bf16_t*)((char*)As + tid * 16);
    bf16_t* lb = (bf16_t*)((char*)Bs + tid * 16);

    for (int kk = 0; kk < D_DIM; kk += 32) {
        gld16(ga + kk, la);
        gld16(gb + kk, lb);
        __syncthreads();
        const bf16x8 a0 = *(const bf16x8*)(As + (wm + 0  + l15) * 32 + quad * 8);
        const bf16x8 a1 = *(const bf16x8*)(As + (wm + 16 + l15) * 32 + quad * 8);
        const bf16x8 b0 = *(const bf16x8*)(Bs + (wn + 0  + l15) * 32 + quad * 8);
        const bf16x8 b1 = *(const bf16x8*)(Bs + (wn + 16 + l15) * 32 + quad * 8);
        acc[0][0] = __builtin_amdgcn_mfma_f32_16x16x32_bf16(a0, b0, acc[0][0], 0, 0, 0);
        acc[0][1] = __builtin_amdgcn_mfma_f32_16x16x32_bf16(a0, b1, acc[0][1], 0, 0, 0);
        acc[1][0] = __builtin_amdgcn_mfma_f32_16x16x32_bf16(a1, b0, acc[1][0], 0, 0, 0);
        acc[1][1] = __builtin_amdgcn_mfma_f32_16x16x32_bf16(a1, b1, acc[1][1], 0, 0, 0);
        __syncthreads();
    }

#pragma unroll
    for (int im = 0; im < 2; ++im)
#pragma unroll
        for (int in = 0; in < 2; ++in)
#pragma unroll
            for (int r = 0; r < 4; ++r) {
                const int j = j0 + wm + im * 16 + quad * 4 + r;
                const int c = c0 + wn + in * 16 + l15;
                const size_t idx = (size_t)j * CTX_N + c;
                Rt[idx] = (bf16_t)(acc[im][in][r] - (float)Vt[idx]);
            }
}

// ---- K2: out[i][j] = W[i][j] - c * sum_c Kt[i][c]*Rt[j][c]  (4096x4096) ----
__global__ __launch_bounds__(256) void k2_update(
    const bf16_t* __restrict__ Kt, const bf16_t* __restrict__ Rt,
    const float* __restrict__ W, float* __restrict__ out)
{
    __shared__ __align__(16) bf16_t As[64 * 32];  // Kt rows (i, c)
    __shared__ __align__(16) bf16_t Bs[64 * 32];  // Rt rows (j, c)

    const int tid = threadIdx.x;
    const int j0 = blockIdx.x * 64;
    const int i0 = blockIdx.y * 64;
    const int lane = tid & 63, wave = tid >> 6;
    const int wm = (wave >> 1) * 32, wn = (wave & 1) * 32;
    const int l15 = lane & 15, quad = lane >> 4;

    f32x4 acc[2][2] = {};

    const int srow = tid >> 2, sseg = (tid & 3) * 8;
    const bf16_t* ga = Kt + (size_t)(i0 + srow) * CTX_N + sseg;
    const bf16_t* gb = Rt + (size_t)(j0 + srow) * CTX_N + sseg;
    bf16_t* la = (bf16_t*)((char*)As + tid * 16);
    bf16_t* lb = (bf16_t*)((char*)Bs + tid * 16);

    for (int cc = 0; cc < CTX_N; cc += 32) {
        gld16(ga + cc, la);
        gld16(gb + cc, lb);
        __syncthreads();
        const bf16x8 a0 = *(const bf16x8*)(As + (wm + 0  + l15) * 32 + quad * 8);
        const bf16x8 a1 = *(const bf16x8*)(As + (wm + 16 + l15) * 32 + quad * 8);
        const bf16x8 b0 = *(const bf16x8*)(Bs + (wn + 0  + l15) * 32 + quad * 8);
        const bf16x8 b1 = *(const bf16x8*)(Bs + (wn + 16 + l15) * 32 + quad * 8);
        acc[0][0] = __builtin_amdgcn_mfma_f32_16x16x32_bf16(a0, b0, acc[0][0], 0, 0, 0);
        acc[0][1] = __builtin_amdgcn_mfma_f32_16x16x32_bf16(a0, b1, acc[0][1], 0, 0, 0);
        acc[1][0] = __builtin_amdgcn_mfma_f32_16x16x32_bf16(a1, b0, acc[1][0], 0, 0, 0);
        acc[1][1] = __builtin_amdgcn_mfma_f32_16x16x32_bf16(a1, b1, acc[1][1], 0, 0, 0);
        __syncthreads();
    }

#pragma unroll
    for (int im = 0; im < 2; ++im)
#pragma unroll
        for (int in = 0; in < 2; ++in)
#pragma unroll
            for (int r = 0; r < 4; ++r) {
                const int i = i0 + wm + im * 16 + quad * 4 + r;
                const int j = j0 + wn + in * 16 + l15;
                const size_t idx = (size_t)i * D_DIM + j;
                out[idx] = W[idx] - UPD_SCALE * acc[im][in][r];
            }
}

extern "C" void kernel_launch(void* const* d_in, const int* in_sizes, int n_in,
                              void* d_out, int out_size, void* d_ws, size_t ws_size,
                              hipStream_t stream) {
    const float* W = (const float*)d_in[0];   // (4096, 4096)
    const float* K = (const float*)d_in[1];   // (512, 4096)
    const float* V = (const float*)d_in[2];   // (512, 4096)
    float* out = (float*)d_out;

    char* ws = (char*)d_ws;                    // 48 MB used
    bf16_t* Wt = (bf16_t*)(ws);                          // (4096,4096) W^T bf16
    bf16_t* Kt = (bf16_t*)(ws + (size_t)32 * 1024 * 1024); // (4096,512) K^T bf16
    bf16_t* Kb = (bf16_t*)(ws + (size_t)36 * 1024 * 1024); // (512,4096) K  bf16
    bf16_t* Vt = (bf16_t*)(ws + (size_t)40 * 1024 * 1024); // (4096,512) V^T bf16
    bf16_t* Rt = (bf16_t*)(ws + (size_t)44 * 1024 * 1024); // (4096,512) R^T bf16

    t_conv<<<dim3(64, 64), 256, 0, stream>>>(W, Wt, nullptr, D_DIM, D_DIM);
    t_conv<<<dim3(64, 8),  256, 0, stream>>>(K, Kt, Kb,      CTX_N, D_DIM);
    t_conv<<<dim3(64, 8),  256, 0, stream>>>(V, Vt, nullptr, CTX_N, D_DIM);
    k1_residual<<<dim3(64, 8),  256, 0, stream>>>(Wt, Kb, Vt, Rt);
    k2_update  <<<dim3(64, 64), 256, 0, stream>>>(Kt, Rt, W, out);
}